// Round 1
// baseline (606.934 us; speedup 1.0000x reference)
//
#include <hip/hip_runtime.h>

// TimestepNorm: B=16, L=4096, D=1024, fp32.
// Chunked parallel scan over L: K1 per-chunk Welford stats, K2 exclusive
// prefix merge (Chan), K3 replay chunk with reference recurrence emitting y.

#define Bn 16
#define Ln 4096
#define Dn 1024
#define Cn 64
#define CLn (Ln / Cn)   // 64
#define EPSf 1e-5f

__global__ __launch_bounds__(256) void tn_chunk_stats(
    const float* __restrict__ x, const int* __restrict__ mask,
    float* __restrict__ mean_ws, float* __restrict__ m2_ws,
    float* __restrict__ cnt_ws)
{
    int idx = blockIdx.x * 256 + threadIdx.x;     // (b*Cn + c)*Dn + d
    int d  = idx & (Dn - 1);
    int bc = idx >> 10;                           // b*Cn + c
    int c  = bc & (Cn - 1);
    int b  = bc >> 6;

    const float* xp = x + ((size_t)b * Ln + (size_t)c * CLn) * Dn + d;
    const int*   mp = mask + b * Ln + c * CLn;

    float n = 0.f, mean = 0.f, M2 = 0.f;
    #pragma unroll 4
    for (int i = 0; i < CLn; ++i) {
        float xv = xp[(size_t)i * Dn];
        if (mp[i] == 0) {                         // valid (wave-uniform branch)
            n += 1.f;
            float delta = xv - mean;
            mean += delta / n;
            M2 += delta * (xv - mean);
        }
    }
    mean_ws[idx] = mean;
    m2_ws[idx]   = M2;
    if (d == 0) cnt_ws[bc] = n;
}

__global__ __launch_bounds__(256) void tn_scan(
    const int* __restrict__ prev_count, const float* __restrict__ prev_mean,
    const float* __restrict__ prev_var,
    float* __restrict__ mean_ws, float* __restrict__ m2_ws,
    const float* __restrict__ cnt_ws, float* __restrict__ cnt_pref,
    float* __restrict__ out_count, float* __restrict__ out_mean,
    float* __restrict__ out_var)
{
    int idx = blockIdx.x * 256 + threadIdx.x;     // b*Dn + d
    int d = idx & (Dn - 1);
    int b = idx >> 10;

    float n    = (float)prev_count[b];            // >= 1 always
    float mean = prev_mean[idx];
    float M2   = prev_var[idx] * n;               // M2 = count * var

    for (int c = 0; c < Cn; ++c) {
        int rc = b * Cn + c;
        int o  = rc * Dn + d;
        float nc  = cnt_ws[rc];
        float mc  = mean_ws[o];
        float m2c = m2_ws[o];
        // write exclusive prefix (in place; this thread owns these slots)
        mean_ws[o] = mean;
        m2_ws[o]   = M2;
        if (d == 0) cnt_pref[rc] = n;
        // Chan merge: (n,mean,M2) <- merge with chunk (nc,mc,m2c)
        float nn = n + nc;                        // >= 1
        float delta = mc - mean;
        float wB = nc / nn;
        mean += delta * wB;
        M2 += m2c + delta * delta * (n * wB);
        n = nn;
    }
    out_mean[idx] = mean;
    out_var[idx]  = M2 / n;
    if (d == 0) out_count[b] = n;
}

__global__ __launch_bounds__(256) void tn_emit(
    const float* __restrict__ x, const int* __restrict__ mask,
    const float* __restrict__ weight, const float* __restrict__ bias,
    const float* __restrict__ mean_ws, const float* __restrict__ m2_ws,
    const float* __restrict__ cnt_pref, float* __restrict__ y)
{
    int idx = blockIdx.x * 256 + threadIdx.x;     // (b*Cn + c)*Dn + d
    int d  = idx & (Dn - 1);
    int bc = idx >> 10;
    int c  = bc & (Cn - 1);
    int b  = bc >> 6;

    size_t base = ((size_t)b * Ln + (size_t)c * CLn) * Dn + d;
    const float* xp = x + base;
    float*       yp = y + base;
    const int*   mp = mask + b * Ln + c * CLn;

    float n    = cnt_pref[bc];
    float mean = mean_ws[idx];
    float M2   = m2_ws[idx];
    float gamma = weight[d] + 1.f;
    float beta  = bias[d];

    #pragma unroll 4
    for (int i = 0; i < CLn; ++i) {
        float xv = xp[(size_t)i * Dn];
        float yv = 0.f;
        if (mp[i] == 0) {                         // valid (wave-uniform)
            n += 1.f;
            float delta = xv - mean;              // x - old_mean
            mean += delta / n;                    // new_mean
            float d2 = xv - mean;                 // x - new_mean
            M2 += delta * d2;
            float var = M2 / n;                   // new_var
            yv = gamma * d2 * rsqrtf(var + EPSf) + beta;
        }
        yp[(size_t)i * Dn] = yv;
    }
}

extern "C" void kernel_launch(void* const* d_in, const int* in_sizes, int n_in,
                              void* d_out, int out_size, void* d_ws, size_t ws_size,
                              hipStream_t stream)
{
    const float* x          = (const float*)d_in[0];
    const int*   prev_count = (const int*)d_in[1];
    const float* prev_mean  = (const float*)d_in[2];
    const float* prev_var   = (const float*)d_in[3];
    const float* weight     = (const float*)d_in[4];
    const float* bias       = (const float*)d_in[5];
    const int*   mask       = (const int*)d_in[6];   // bool -> int32 per harness doc

    // outputs: y [B*L*D], count [B], mean [B*D], var [B*D] (all fp32, concat)
    float* y         = (float*)d_out;
    float* out_count = y + (size_t)Bn * Ln * Dn;
    float* out_mean  = out_count + Bn;
    float* out_var   = out_mean + (size_t)Bn * Dn;

    // workspace: mean_ws/m2_ws [B*Cn*Dn] each, cnt_ws/cnt_pref [B*Cn] each
    float* mean_ws  = (float*)d_ws;
    float* m2_ws    = mean_ws + (size_t)Bn * Cn * Dn;
    float* cnt_ws   = m2_ws + (size_t)Bn * Cn * Dn;
    float* cnt_pref = cnt_ws + Bn * Cn;

    tn_chunk_stats<<<(Bn * Cn * Dn) / 256, 256, 0, stream>>>(
        x, mask, mean_ws, m2_ws, cnt_ws);
    tn_scan<<<(Bn * Dn) / 256, 256, 0, stream>>>(
        prev_count, prev_mean, prev_var, mean_ws, m2_ws, cnt_ws, cnt_pref,
        out_count, out_mean, out_var);
    tn_emit<<<(Bn * Cn * Dn) / 256, 256, 0, stream>>>(
        x, mask, weight, bias, mean_ws, m2_ws, cnt_pref, y);
}

// Round 2
// 510.922 us; speedup vs baseline: 1.1879x; 1.1879x over previous
//
#include <hip/hip_runtime.h>

// TimestepNorm: B=16, L=4096, D=1024, fp32.
// Chunked parallel scan over L: K1 per-chunk Welford stats (float4 over d),
// K2 exclusive prefix merge (Chan, float4), K3 replay chunk emitting y
// (float4, x load skipped on masked rows — mask is block-uniform).

#define Bn 16
#define Ln 4096
#define Dn 1024
#define D4 (Dn / 4)     // 256 float4 groups
#define Cn 64
#define CLn (Ln / Cn)   // 64
#define EPSf 1e-5f

__global__ __launch_bounds__(256) void tn_chunk_stats(
    const float* __restrict__ x, const int* __restrict__ mask,
    float4* __restrict__ mean_ws, float4* __restrict__ m2_ws,
    float* __restrict__ cnt_ws)
{
    int idx = blockIdx.x * 256 + threadIdx.x;     // (b*Cn + c)*D4 + d4
    int d4 = idx & (D4 - 1);
    int bc = idx >> 8;                            // b*Cn + c
    int c  = bc & (Cn - 1);
    int b  = bc >> 6;

    const float4* xp = (const float4*)(x + ((size_t)b * Ln + (size_t)c * CLn) * Dn) + d4;
    const int*    mp = mask + b * Ln + c * CLn;

    float n = 0.f;
    float4 mean = {0.f, 0.f, 0.f, 0.f};
    float4 M2   = {0.f, 0.f, 0.f, 0.f};
    #pragma unroll 8
    for (int i = 0; i < CLn; ++i) {
        float4 xv = xp[(size_t)i * D4];           // unconditional: keep MLP deep
        if (mp[i] == 0) {                         // block-uniform branch
            n += 1.f;
            float rn = 1.f / n;
            float dx, dy, dz, dw;
            dx = xv.x - mean.x; mean.x += dx * rn; M2.x += dx * (xv.x - mean.x);
            dy = xv.y - mean.y; mean.y += dy * rn; M2.y += dy * (xv.y - mean.y);
            dz = xv.z - mean.z; mean.z += dz * rn; M2.z += dz * (xv.z - mean.z);
            dw = xv.w - mean.w; mean.w += dw * rn; M2.w += dw * (xv.w - mean.w);
        }
    }
    mean_ws[idx] = mean;
    m2_ws[idx]   = M2;
    if (d4 == 0) cnt_ws[bc] = n;
}

__global__ __launch_bounds__(256) void tn_scan(
    const int* __restrict__ prev_count, const float4* __restrict__ prev_mean,
    const float4* __restrict__ prev_var,
    float4* __restrict__ mean_ws, float4* __restrict__ m2_ws,
    const float* __restrict__ cnt_ws, float* __restrict__ cnt_pref,
    float* __restrict__ out_count, float4* __restrict__ out_mean,
    float4* __restrict__ out_var)
{
    int idx = blockIdx.x * 256 + threadIdx.x;     // b*D4 + d4
    int d4 = idx & (D4 - 1);
    int b  = idx >> 8;

    float  n    = (float)prev_count[b];           // >= 1 always
    float4 mean = prev_mean[idx];
    float4 var  = prev_var[idx];
    float4 M2   = {var.x * n, var.y * n, var.z * n, var.w * n};

    #pragma unroll 4
    for (int c = 0; c < Cn; ++c) {
        int rc = b * Cn + c;
        int o  = rc * D4 + d4;
        float  nc  = cnt_ws[rc];
        float4 mc  = mean_ws[o];
        float4 m2c = m2_ws[o];
        // write exclusive prefix (in place; this thread owns these slots)
        mean_ws[o] = mean;
        m2_ws[o]   = M2;
        if (d4 == 0) cnt_pref[rc] = n;
        // Chan merge
        float nn = n + nc;                        // >= 1
        float wB = nc / nn;
        float s  = n * wB;
        float dx = mc.x - mean.x, dy = mc.y - mean.y,
              dz = mc.z - mean.z, dw = mc.w - mean.w;
        mean.x += dx * wB; mean.y += dy * wB;
        mean.z += dz * wB; mean.w += dw * wB;
        M2.x += m2c.x + dx * dx * s; M2.y += m2c.y + dy * dy * s;
        M2.z += m2c.z + dz * dz * s; M2.w += m2c.w + dw * dw * s;
        n = nn;
    }
    out_mean[idx] = mean;
    float rn = 1.f / n;
    out_var[idx] = {M2.x * rn, M2.y * rn, M2.z * rn, M2.w * rn};
    if (d4 == 0) out_count[b] = n;
}

__global__ __launch_bounds__(256) void tn_emit(
    const float* __restrict__ x, const int* __restrict__ mask,
    const float* __restrict__ weight, const float* __restrict__ bias,
    const float4* __restrict__ mean_ws, const float4* __restrict__ m2_ws,
    const float* __restrict__ cnt_pref, float* __restrict__ y)
{
    int idx = blockIdx.x * 256 + threadIdx.x;     // (b*Cn + c)*D4 + d4
    int d4 = idx & (D4 - 1);
    int bc = idx >> 8;
    int c  = bc & (Cn - 1);
    int b  = bc >> 6;

    size_t base = ((size_t)b * Ln + (size_t)c * CLn) * Dn;
    const float4* xp = (const float4*)(x + base) + d4;
    float4*       yp = (float4*)(y + base) + d4;
    const int*    mp = mask + b * Ln + c * CLn;

    float  n    = cnt_pref[bc];
    float4 mean = mean_ws[idx];
    float4 M2   = m2_ws[idx];
    const float4 w4 = ((const float4*)weight)[d4];
    const float4 b4 = ((const float4*)bias)[d4];
    float gx = w4.x + 1.f, gy = w4.y + 1.f, gz = w4.z + 1.f, gw = w4.w + 1.f;

    #pragma unroll 4
    for (int i = 0; i < CLn; ++i) {
        float4 yv = {0.f, 0.f, 0.f, 0.f};
        if (mp[i] == 0) {                         // block-uniform: skip masked rows
            float4 xv = xp[(size_t)i * D4];
            n += 1.f;
            float rn = 1.f / n;
            float dx, d2;
            dx = xv.x - mean.x; mean.x += dx * rn; d2 = xv.x - mean.x;
            M2.x += dx * d2; yv.x = gx * d2 * rsqrtf(M2.x * rn + EPSf) + b4.x;
            dx = xv.y - mean.y; mean.y += dx * rn; d2 = xv.y - mean.y;
            M2.y += dx * d2; yv.y = gy * d2 * rsqrtf(M2.y * rn + EPSf) + b4.y;
            dx = xv.z - mean.z; mean.z += dx * rn; d2 = xv.z - mean.z;
            M2.z += dx * d2; yv.z = gz * d2 * rsqrtf(M2.z * rn + EPSf) + b4.z;
            dx = xv.w - mean.w; mean.w += dx * rn; d2 = xv.w - mean.w;
            M2.w += dx * d2; yv.w = gw * d2 * rsqrtf(M2.w * rn + EPSf) + b4.w;
        }
        yp[(size_t)i * D4] = yv;
    }
}

extern "C" void kernel_launch(void* const* d_in, const int* in_sizes, int n_in,
                              void* d_out, int out_size, void* d_ws, size_t ws_size,
                              hipStream_t stream)
{
    const float* x          = (const float*)d_in[0];
    const int*   prev_count = (const int*)d_in[1];
    const float* prev_mean  = (const float*)d_in[2];
    const float* prev_var   = (const float*)d_in[3];
    const float* weight     = (const float*)d_in[4];
    const float* bias       = (const float*)d_in[5];
    const int*   mask       = (const int*)d_in[6];   // bool arrives as int32

    // outputs: y [B*L*D], count [B], mean [B*D], var [B*D] (all fp32, concat)
    float* y         = (float*)d_out;
    float* out_count = y + (size_t)Bn * Ln * Dn;
    float* out_mean  = out_count + Bn;
    float* out_var   = out_mean + (size_t)Bn * Dn;

    // workspace: mean_ws/m2_ws [B*Cn*Dn] floats each, cnt_ws/cnt_pref [B*Cn]
    float* mean_ws  = (float*)d_ws;
    float* m2_ws    = mean_ws + (size_t)Bn * Cn * Dn;
    float* cnt_ws   = m2_ws + (size_t)Bn * Cn * Dn;
    float* cnt_pref = cnt_ws + Bn * Cn;

    tn_chunk_stats<<<(Bn * Cn * D4) / 256, 256, 0, stream>>>(
        x, mask, (float4*)mean_ws, (float4*)m2_ws, cnt_ws);
    tn_scan<<<(Bn * D4) / 256, 256, 0, stream>>>(
        prev_count, (const float4*)prev_mean, (const float4*)prev_var,
        (float4*)mean_ws, (float4*)m2_ws, cnt_ws, cnt_pref,
        out_count, (float4*)out_mean, (float4*)out_var);
    tn_emit<<<(Bn * Cn * D4) / 256, 256, 0, stream>>>(
        x, mask, weight, bias, (const float4*)mean_ws, (const float4*)m2_ws,
        cnt_pref, y);
}

// Round 3
// 502.191 us; speedup vs baseline: 1.2086x; 1.0174x over previous
//
#include <hip/hip_runtime.h>

// TimestepNorm: B=16, L=4096, D=1024, fp32.
// K1: per-chunk Welford stats (float4 over d), Cn=128 chunks of 32 rows.
// K2: Kogge-Stone wave scan over chunks (Chan merge), 1 wave per (b,d4).
// K3: replay chunk from exclusive prefix, emit y (skip x loads on masked rows).
// Workspace stats layout transposed: [b][d4][c] so K2 lanes load contiguous.

#define Bn 16
#define Ln 4096
#define Dn 1024
#define D4 (Dn / 4)     // 256 float4 groups
#define Cn 128
#define CLn (Ln / Cn)   // 32
#define EPSf 1e-5f

struct St { float n; float4 m; float4 s; };   // count, mean, M2 (= n*var)

__device__ __forceinline__ St chan_merge(const St& A, const St& B) {
    St R;
    R.n = A.n + B.n;
    float wB = B.n / fmaxf(R.n, 1.f);          // guard n==0 (all-padded)
    float sc = A.n * wB;
    float dx = B.m.x - A.m.x, dy = B.m.y - A.m.y,
          dz = B.m.z - A.m.z, dw = B.m.w - A.m.w;
    R.m.x = A.m.x + dx * wB; R.m.y = A.m.y + dy * wB;
    R.m.z = A.m.z + dz * wB; R.m.w = A.m.w + dw * wB;
    R.s.x = A.s.x + B.s.x + dx * dx * sc; R.s.y = A.s.y + B.s.y + dy * dy * sc;
    R.s.z = A.s.z + B.s.z + dz * dz * sc; R.s.w = A.s.w + B.s.w + dw * dw * sc;
    return R;
}

__device__ __forceinline__ St shfl_up_st(const St& v, int delta) {
    St r;
    r.n   = __shfl_up(v.n,   delta, 64);
    r.m.x = __shfl_up(v.m.x, delta, 64); r.m.y = __shfl_up(v.m.y, delta, 64);
    r.m.z = __shfl_up(v.m.z, delta, 64); r.m.w = __shfl_up(v.m.w, delta, 64);
    r.s.x = __shfl_up(v.s.x, delta, 64); r.s.y = __shfl_up(v.s.y, delta, 64);
    r.s.z = __shfl_up(v.s.z, delta, 64); r.s.w = __shfl_up(v.s.w, delta, 64);
    return r;
}

__global__ __launch_bounds__(256) void tn_chunk_stats(
    const float* __restrict__ x, const int* __restrict__ mask,
    float4* __restrict__ mean_ws, float4* __restrict__ m2_ws,
    float* __restrict__ cnt_ws)
{
    int idx = blockIdx.x * 256 + threadIdx.x;     // (b*Cn + c)*D4 + d4
    int d4 = idx & (D4 - 1);
    int bc = idx >> 8;                            // b*Cn + c
    int c  = bc & (Cn - 1);
    int b  = bc >> 7;

    const float4* xp = (const float4*)(x + ((size_t)b * Ln + (size_t)c * CLn) * Dn) + d4;
    const int*    mp = mask + b * Ln + c * CLn;

    float n = 0.f;
    float4 mean = {0.f, 0.f, 0.f, 0.f};
    float4 M2   = {0.f, 0.f, 0.f, 0.f};
    #pragma unroll 8
    for (int i = 0; i < CLn; ++i) {
        float4 xv = xp[(size_t)i * D4];           // unconditional: keep MLP deep
        if (mp[i] == 0) {                         // block-uniform branch
            n += 1.f;
            float rn = 1.f / n;
            float dx;
            dx = xv.x - mean.x; mean.x += dx * rn; M2.x += dx * (xv.x - mean.x);
            dx = xv.y - mean.y; mean.y += dx * rn; M2.y += dx * (xv.y - mean.y);
            dx = xv.z - mean.z; mean.z += dx * rn; M2.z += dx * (xv.z - mean.z);
            dx = xv.w - mean.w; mean.w += dx * rn; M2.w += dx * (xv.w - mean.w);
        }
    }
    int o = (b * D4 + d4) * Cn + c;               // transposed [b][d4][c]
    mean_ws[o] = mean;
    m2_ws[o]   = M2;
    if (d4 == 0) cnt_ws[bc] = n;
}

__global__ __launch_bounds__(256) void tn_scan(
    const int* __restrict__ prev_count, const float4* __restrict__ prev_mean,
    const float4* __restrict__ prev_var,
    float4* __restrict__ mean_ws, float4* __restrict__ m2_ws,
    const float* __restrict__ cnt_ws, float* __restrict__ cnt_pref,
    float* __restrict__ out_count, float4* __restrict__ out_mean,
    float4* __restrict__ out_var)
{
    int wv   = (blockIdx.x * 256 + threadIdx.x) >> 6;  // global wave: b*D4 + d4
    int lane = threadIdx.x & 63;
    int b  = wv >> 8;
    int d4 = wv & (D4 - 1);
    int base = (b * D4 + d4) * Cn;
    int c0 = 2 * lane, c1 = 2 * lane + 1;

    St s0, s1;
    s0.n = cnt_ws[b * Cn + c0]; s0.m = mean_ws[base + c0]; s0.s = m2_ws[base + c0];
    s1.n = cnt_ws[b * Cn + c1]; s1.m = mean_ws[base + c1]; s1.s = m2_ws[base + c1];

    St incl = chan_merge(s0, s1);                 // per-lane pair stat
    #pragma unroll
    for (int off = 1; off < 64; off <<= 1) {
        St t = shfl_up_st(incl, off);
        if (lane >= off) incl = chan_merge(t, incl);
    }
    St epp = shfl_up_st(incl, 1);                 // exclusive pair prefix
    if (lane == 0) {
        epp.n = 0.f;
        epp.m = {0.f, 0.f, 0.f, 0.f};
        epp.s = {0.f, 0.f, 0.f, 0.f};
    }

    float np = (float)prev_count[b];              // >= 1 always
    St P;
    P.n = np;
    P.m = prev_mean[b * D4 + d4];
    float4 vp = prev_var[b * D4 + d4];
    P.s = {vp.x * np, vp.y * np, vp.z * np, vp.w * np};

    St pref0 = chan_merge(P, epp);
    St pref1 = chan_merge(pref0, s0);

    mean_ws[base + c0] = pref0.m; m2_ws[base + c0] = pref0.s;
    mean_ws[base + c1] = pref1.m; m2_ws[base + c1] = pref1.s;
    if (d4 == 0) {
        cnt_pref[b * Cn + c0] = pref0.n;
        cnt_pref[b * Cn + c1] = pref1.n;
    }

    if (lane == 63) {
        St tot = chan_merge(P, incl);
        out_mean[b * D4 + d4] = tot.m;
        float rn = 1.f / tot.n;
        out_var[b * D4 + d4] = {tot.s.x * rn, tot.s.y * rn, tot.s.z * rn, tot.s.w * rn};
        if (d4 == 0) out_count[b] = tot.n;
    }
}

__global__ __launch_bounds__(256) void tn_emit(
    const float* __restrict__ x, const int* __restrict__ mask,
    const float* __restrict__ weight, const float* __restrict__ bias,
    const float4* __restrict__ mean_ws, const float4* __restrict__ m2_ws,
    const float* __restrict__ cnt_pref, float* __restrict__ y)
{
    int idx = blockIdx.x * 256 + threadIdx.x;     // (b*Cn + c)*D4 + d4
    int d4 = idx & (D4 - 1);
    int bc = idx >> 8;
    int c  = bc & (Cn - 1);
    int b  = bc >> 7;

    size_t gbase = ((size_t)b * Ln + (size_t)c * CLn) * Dn;
    const float4* xp = (const float4*)(x + gbase) + d4;
    float4*       yp = (float4*)(y + gbase) + d4;
    const int*    mp = mask + b * Ln + c * CLn;

    int o = (b * D4 + d4) * Cn + c;               // transposed [b][d4][c]
    float  n    = cnt_pref[bc];
    float4 mean = mean_ws[o];
    float4 M2   = m2_ws[o];
    const float4 w4 = ((const float4*)weight)[d4];
    const float4 b4 = ((const float4*)bias)[d4];
    float gx = w4.x + 1.f, gy = w4.y + 1.f, gz = w4.z + 1.f, gw = w4.w + 1.f;

    #pragma unroll 4
    for (int i = 0; i < CLn; ++i) {
        float4 yv = {0.f, 0.f, 0.f, 0.f};
        if (mp[i] == 0) {                         // block-uniform: skip masked rows
            float4 xv = xp[(size_t)i * D4];
            n += 1.f;
            float rn = 1.f / n;
            float dx, d2;
            dx = xv.x - mean.x; mean.x += dx * rn; d2 = xv.x - mean.x;
            M2.x += dx * d2; yv.x = gx * d2 * rsqrtf(M2.x * rn + EPSf) + b4.x;
            dx = xv.y - mean.y; mean.y += dx * rn; d2 = xv.y - mean.y;
            M2.y += dx * d2; yv.y = gy * d2 * rsqrtf(M2.y * rn + EPSf) + b4.y;
            dx = xv.z - mean.z; mean.z += dx * rn; d2 = xv.z - mean.z;
            M2.z += dx * d2; yv.z = gz * d2 * rsqrtf(M2.z * rn + EPSf) + b4.z;
            dx = xv.w - mean.w; mean.w += dx * rn; d2 = xv.w - mean.w;
            M2.w += dx * d2; yv.w = gw * d2 * rsqrtf(M2.w * rn + EPSf) + b4.w;
        }
        yp[(size_t)i * D4] = yv;
    }
}

extern "C" void kernel_launch(void* const* d_in, const int* in_sizes, int n_in,
                              void* d_out, int out_size, void* d_ws, size_t ws_size,
                              hipStream_t stream)
{
    const float* x          = (const float*)d_in[0];
    const int*   prev_count = (const int*)d_in[1];
    const float* prev_mean  = (const float*)d_in[2];
    const float* prev_var   = (const float*)d_in[3];
    const float* weight     = (const float*)d_in[4];
    const float* bias       = (const float*)d_in[5];
    const int*   mask       = (const int*)d_in[6];   // bool arrives as int32

    // outputs: y [B*L*D], count [B], mean [B*D], var [B*D] (all fp32, concat)
    float* y         = (float*)d_out;
    float* out_count = y + (size_t)Bn * Ln * Dn;
    float* out_mean  = out_count + Bn;
    float* out_var   = out_mean + (size_t)Bn * Dn;

    // workspace: mean_ws/m2_ws [B*D4*Cn] float4 each, cnt_ws/cnt_pref [B*Cn]
    float4* mean_ws  = (float4*)d_ws;
    float4* m2_ws    = mean_ws + (size_t)Bn * D4 * Cn;
    float*  cnt_ws   = (float*)(m2_ws + (size_t)Bn * D4 * Cn);
    float*  cnt_pref = cnt_ws + Bn * Cn;

    tn_chunk_stats<<<(Bn * Cn * D4) / 256, 256, 0, stream>>>(
        x, mask, mean_ws, m2_ws, cnt_ws);
    tn_scan<<<(Bn * D4 * 64) / 256, 256, 0, stream>>>(
        prev_count, (const float4*)prev_mean, (const float4*)prev_var,
        mean_ws, m2_ws, cnt_ws, cnt_pref,
        out_count, (float4*)out_mean, (float4*)out_var);
    tn_emit<<<(Bn * Cn * D4) / 256, 256, 0, stream>>>(
        x, mask, weight, bias, mean_ws, m2_ws, cnt_pref, y);
}